// Round 1
// baseline (22040.172 us; speedup 1.0000x reference)
//
#include <hip/hip_runtime.h>
#include <stdint.h>

// ---------------- problem constants ----------------
#define EMBD   256
#define HID    512
#define KTOT   768            // EMB + HID
#define NCLS   50257
#define NBATCH 64
#define STEPS  512

// ---------------- persistent-kernel partition ----------------
#define NGROUP 8               // batch groups
#define GB     8               // batches per group
#define BPG    32              // blocks per group (hidden split)
#define HS     16              // hidden units per block -> 64 gate rows
#define UPITCH 776             // u row pitch in bf16 elems (768 + 8 pad: kills 16-way LDS bank conflict)

typedef float f32x4  __attribute__((ext_vector_type(4)));
typedef short bf16x8 __attribute__((ext_vector_type(8)));

__device__ __forceinline__ unsigned bf16_rne(float f) {
  unsigned u = __float_as_uint(f);
  return (u + 0x7FFFu + ((u >> 16) & 1u)) >> 16;
}
__device__ __forceinline__ float bf16_to_f32(unsigned b) {
  return __uint_as_float(b << 16);
}

// ============ kernel 1: embedding gather + bf16 hi/lo pack ============
// emb_hl[tok][k] = hi_bits | (lo_bits<<16), tok = b*512 + t
__global__ void emb_prep(const int* __restrict__ x, const float* __restrict__ emb,
                         unsigned* __restrict__ emb_hl) {
  int base = blockIdx.x * 4;
  int k = threadIdx.x;
  for (int it = 0; it < 4; ++it) {
    int tok = base + it;
    int id = x[tok];
    float w = emb[(size_t)id * EMBD + k];
    unsigned hb = bf16_rne(w);
    unsigned lb = bf16_rne(w - bf16_to_f32(hb));
    emb_hl[(size_t)tok * EMBD + k] = hb | (lb << 16);
  }
}

// ============ kernel 2: persistent LSTM recurrence ============
// grid 256 blocks (cooperative, 1/CU). block = 512 thr (8 waves).
// wave == local batch m for the epilogue; K split 3 k-tiles/wave for MFMA.
// W slice lives in VGPRs as B-fragments (hi+lo) for all 512 steps.
__global__ __launch_bounds__(512, 2) void lstm_persist(
    const float* __restrict__ Ww, const float* __restrict__ Wb,
    const unsigned* __restrict__ emb_hl,
    unsigned* __restrict__ h_hl, int* __restrict__ ctr,
    float* __restrict__ hfinal)
{
  __shared__ __align__(16) unsigned short u_hi[16 * UPITCH];
  __shared__ __align__(16) unsigned short u_lo[16 * UPITCH];
  __shared__ __align__(16) float red[8 * 4 * 64 * 4];   // [wave][ntile][lane][4] partials

  const int tid  = threadIdx.x;
  const int wave = tid >> 6;
  const int lane = tid & 63;
  const int g = blockIdx.x >> 5;    // batch group 0..7
  const int s = blockIdx.x & 31;    // hidden slice 0..31

  // zero all u rows once (rows 8..15 are M-padding and stay zero forever)
  for (int i = tid; i < 16 * UPITCH; i += 512) { u_hi[i] = 0; u_lo[i] = 0; }

  // ---- load W B-fragments into registers (one time) ----
  // B-frag (KxN): lane holds B[k = kt*32 + (lane>>4)*8 + j][n = lane&15],
  // i.e. 8 consecutive cols of W row (ntile*512 + s*16 + (lane&15)); ntile == gate.
  const int cn = lane & 15;
  const int qk = (lane >> 4) * 8;
  bf16x8 whi[3][4], wlo[3][4];
#pragma unroll
  for (int i = 0; i < 3; ++i) {
    int kt = wave * 3 + i;
    int k0 = kt * 32 + qk;
#pragma unroll
    for (int nt = 0; nt < 4; ++nt) {
      int row = nt * 512 + s * HS + cn;
      const float* src = Ww + (size_t)row * KTOT + k0;
      float4 w0 = *(const float4*)src;
      float4 w1 = *(const float4*)(src + 4);
      float wv[8] = {w0.x, w0.y, w0.z, w0.w, w1.x, w1.y, w1.z, w1.w};
#pragma unroll
      for (int j = 0; j < 8; ++j) {
        unsigned hb = bf16_rne(wv[j]);
        unsigned lb = bf16_rne(wv[j] - bf16_to_f32(hb));
        whi[i][nt][j] = (short)hb;
        wlo[i][nt][j] = (short)lb;
      }
    }
  }

  // this thread owns gate output (m = wave, n = lane) after reduction.
  // C/D frag: lane rl=((m>>2)<<4)|(n&15), reg rj=m&3 holds D[m][n].
  const float bias = Wb[(lane >> 4) * 512 + s * HS + (lane & 15)];
  const int rl = ((wave >> 2) << 4) | (lane & 15);
  const int rj = wave & 3;

  float Cst = 0.0f;  // cell state for (batch=wave, unit=lane) on lanes<16

  const unsigned* embg = emb_hl + (size_t)(g * GB) * STEPS * EMBD;
  unsigned* hbase = h_hl + (size_t)g * 3 * GB * HID;
  int* ctrg = ctr + g * STEPS;

  __syncthreads();

  for (int step = 0; step < STEPS; ++step) {
    // ---- wait for previous step's h from all 32 blocks of this group ----
    if (step > 0) {
      if (tid == 0) {
        while (__hip_atomic_load(&ctrg[step - 1], __ATOMIC_ACQUIRE,
                                 __HIP_MEMORY_SCOPE_AGENT) < BPG)
          __builtin_amdgcn_s_sleep(1);
      }
      __syncthreads();
    }
    // ---- stage u = [emb_t (256) | h_t (512)] as bf16 hi/lo into LDS ----
    {   // emb part: 8*256 = 2048 u32, 4 per thread
      int f0 = tid * 4;
      int b = f0 >> 8, k0 = f0 & 255;
      uint4 v = *(const uint4*)(embg + ((size_t)b * STEPS + step) * EMBD + k0);
      unsigned h01 = (v.x & 0xFFFFu) | ((v.y & 0xFFFFu) << 16);
      unsigned h23 = (v.z & 0xFFFFu) | ((v.w & 0xFFFFu) << 16);
      unsigned l01 = (v.x >> 16) | (v.y & 0xFFFF0000u);
      unsigned l23 = (v.z >> 16) | (v.w & 0xFFFF0000u);
      *(uint2*)&u_hi[b * UPITCH + k0] = make_uint2(h01, h23);
      *(uint2*)&u_lo[b * UPITCH + k0] = make_uint2(l01, l23);
    }
    const unsigned* hin = hbase + (step % 3) * (GB * HID);
#pragma unroll
    for (int i = 0; i < 2; ++i) {   // h part: 8*512 = 4096 u32, 8 per thread
      int f0 = (tid + i * 512) * 4;
      int b = f0 >> 9, k0 = f0 & 511;
      uint4 v = *(const uint4*)(hin + b * HID + k0);
      unsigned h01 = (v.x & 0xFFFFu) | ((v.y & 0xFFFFu) << 16);
      unsigned h23 = (v.z & 0xFFFFu) | ((v.w & 0xFFFFu) << 16);
      unsigned l01 = (v.x >> 16) | (v.y & 0xFFFF0000u);
      unsigned l23 = (v.z >> 16) | (v.w & 0xFFFF0000u);
      *(uint2*)&u_hi[b * UPITCH + EMBD + k0] = make_uint2(h01, h23);
      *(uint2*)&u_lo[b * UPITCH + EMBD + k0] = make_uint2(l01, l23);
    }
    __syncthreads();

    // ---- gates = u @ W_sliceT : MFMA, k-split over waves ----
    f32x4 acc[4] = {{0.f,0.f,0.f,0.f},{0.f,0.f,0.f,0.f},
                    {0.f,0.f,0.f,0.f},{0.f,0.f,0.f,0.f}};
#pragma unroll
    for (int i = 0; i < 3; ++i) {
      int k0 = (wave * 3 + i) * 32 + qk;
      int m = lane & 15;
      bf16x8 ahi = *(const bf16x8*)&u_hi[m * UPITCH + k0];
      bf16x8 alo = *(const bf16x8*)&u_lo[m * UPITCH + k0];
#pragma unroll
      for (int nt = 0; nt < 4; ++nt) {
        acc[nt] = __builtin_amdgcn_mfma_f32_16x16x32_bf16(ahi, whi[i][nt], acc[nt], 0, 0, 0);
        acc[nt] = __builtin_amdgcn_mfma_f32_16x16x32_bf16(ahi, wlo[i][nt], acc[nt], 0, 0, 0);
        acc[nt] = __builtin_amdgcn_mfma_f32_16x16x32_bf16(alo, whi[i][nt], acc[nt], 0, 0, 0);
      }
    }
#pragma unroll
    for (int nt = 0; nt < 4; ++nt)
      *(f32x4*)&red[(((wave * 4 + nt) * 64) + lane) * 4] = acc[nt];
    __syncthreads();

    // ---- k-split reduction: thread owns (m=wave, n=lane) ----
    float gsum = bias;
#pragma unroll
    for (int w = 0; w < 8; ++w)
      gsum += red[(((w * 4 + (lane >> 4)) * 64) + rl) * 4 + rj];

    // ---- nonlinearities: lanes 0-15 f, 16-31 i, 32-47 o, 48-63 c~ ----
    float scl = (lane >= 48) ? 2.0f : 1.0f;
    float y = 1.0f / (1.0f + __expf(-gsum * scl));
    float act = (lane >= 48) ? (2.0f * y - 1.0f) : y;   // tanh via sigmoid
    float ig = __shfl(act, lane + 16);
    float og = __shfl(act, lane + 32);
    float cg = __shfl(act, lane + 48);
    if (lane < 16) {
      Cst = act * Cst + ig * cg;
      float t2 = 1.0f / (1.0f + __expf(-2.0f * Cst));
      float hv = og * (2.0f * t2 - 1.0f);
      unsigned hb = bf16_rne(hv);
      unsigned lb = bf16_rne(hv - bf16_to_f32(hb));
      unsigned* hout = hbase + ((step + 1) % 3) * (GB * HID);
      hout[wave * HID + s * HS + lane] = hb | (lb << 16);
      if (step == STEPS - 1)
        hfinal[(size_t)(g * GB + wave) * HID + s * HS + lane] = hv;
    }
    __threadfence();
    __syncthreads();
    if (tid == 0)
      __hip_atomic_fetch_add(&ctrg[step], 1, __ATOMIC_RELEASE,
                             __HIP_MEMORY_SCOPE_AGENT);
  }
}

// ============ kernel 3: out = h_final @ fcT + bias (MFMA hi/lo) ============
__device__ __forceinline__ void cvt8(const float4& a, const float4& b,
                                     bf16x8& hi, bf16x8& lo) {
  float v[8] = {a.x, a.y, a.z, a.w, b.x, b.y, b.z, b.w};
#pragma unroll
  for (int j = 0; j < 8; ++j) {
    unsigned hb = bf16_rne(v[j]);
    hi[j] = (short)hb;
    lo[j] = (short)bf16_rne(v[j] - bf16_to_f32(hb));
  }
}

__global__ __launch_bounds__(512) void fc_mfma(
    const float* __restrict__ hfinal, const float* __restrict__ fcw,
    const float* __restrict__ fcb, float* __restrict__ out)
{
  const int tid = threadIdx.x, wave = tid >> 6, lane = tid & 63;
  const int cn = lane & 15;
  const int qk = (lane >> 4) * 8;
  const int cls  = blockIdx.x * 128 + wave * 16 + cn;
  const int clsc = cls < NCLS ? cls : NCLS - 1;

  f32x4 acc[4] = {{0.f,0.f,0.f,0.f},{0.f,0.f,0.f,0.f},
                  {0.f,0.f,0.f,0.f},{0.f,0.f,0.f,0.f}};
#pragma unroll 2
  for (int kt = 0; kt < 16; ++kt) {
    int k0 = kt * 32 + qk;
    const float* bp = fcw + (size_t)clsc * HID + k0;
    float4 b0 = *(const float4*)bp;
    float4 b1 = *(const float4*)(bp + 4);
    bf16x8 bhi, blo;
    cvt8(b0, b1, bhi, blo);
#pragma unroll
    for (int mt = 0; mt < 4; ++mt) {
      const float* ap = hfinal + (size_t)(mt * 16 + cn) * HID + k0;
      float4 a0 = *(const float4*)ap;
      float4 a1 = *(const float4*)(ap + 4);
      bf16x8 ahi, alo;
      cvt8(a0, a1, ahi, alo);
      acc[mt] = __builtin_amdgcn_mfma_f32_16x16x32_bf16(ahi, bhi, acc[mt], 0, 0, 0);
      acc[mt] = __builtin_amdgcn_mfma_f32_16x16x32_bf16(ahi, blo, acc[mt], 0, 0, 0);
      acc[mt] = __builtin_amdgcn_mfma_f32_16x16x32_bf16(alo, bhi, acc[mt], 0, 0, 0);
    }
  }
  if (cls < NCLS) {
    float bias = fcb[cls];
#pragma unroll
    for (int mt = 0; mt < 4; ++mt)
#pragma unroll
      for (int j = 0; j < 4; ++j) {
        int m = mt * 16 + (lane >> 4) * 4 + j;
        out[(size_t)m * NCLS + cls] = acc[mt][j] + bias;
      }
  }
}

// ============ launcher ============
extern "C" void kernel_launch(void* const* d_in, const int* in_sizes, int n_in,
                              void* d_out, int out_size, void* d_ws, size_t ws_size,
                              hipStream_t stream) {
  const int*   x   = (const int*)d_in[0];
  const float* emb = (const float*)d_in[1];
  const float* Ww  = (const float*)d_in[2];
  const float* Wb  = (const float*)d_in[3];
  const float* fcw = (const float*)d_in[4];
  const float* fcb = (const float*)d_in[5];
  float* out = (float*)d_out;

  // workspace carve-up
  char* ws = (char*)d_ws;
  int*      ctr    = (int*)ws;                               //  16,384 B (8 grp x 512 steps)
  unsigned* h_hl   = (unsigned*)(ws + 16384);                // 393,216 B (8 grp x 3 slots x 8 x 512)
  float*    hfinal = (float*)(ws + 16384 + 393216);          // 131,072 B
  unsigned* emb_hl = (unsigned*)(ws + 16384 + 393216 + 131072); // 33,554,432 B

  // zero counters + h triple-buffer (h_0 = 0)
  hipMemsetAsync(d_ws, 0, 16384 + 393216, stream);

  emb_prep<<<8192, 256, 0, stream>>>(x, emb, emb_hl);

  void* args[] = { (void*)&Ww, (void*)&Wb, (void*)&emb_hl,
                   (void*)&h_hl, (void*)&ctr, (void*)&hfinal };
  hipLaunchCooperativeKernel((void*)lstm_persist, dim3(256), dim3(512),
                             args, 0, stream);

  fc_mfma<<<(NCLS + 127) / 128, 512, 0, stream>>>(hfinal, fcw, fcb, out);
}

// Round 2
// 2264.293 us; speedup vs baseline: 9.7338x; 9.7338x over previous
//
#include <hip/hip_runtime.h>
#include <stdint.h>

// ---------------- problem constants ----------------
#define EMBD   256
#define HID    512
#define KTOT   768            // EMB + HID
#define NCLS   50257
#define NBATCH 64
#define STEPS  512

// ---------------- persistent-kernel partition ----------------
#define NGROUP 8               // batch groups
#define GB     8               // batches per group
#define BPG    32              // blocks per group (hidden split)
#define HS     16              // hidden units per block -> 64 gate rows
#define UPITCH 776             // u row pitch in bf16 elems (768 + 8 pad)

typedef float f32x4  __attribute__((ext_vector_type(4)));
typedef short bf16x8 __attribute__((ext_vector_type(8)));

__device__ __forceinline__ unsigned bf16_rne(float f) {
  unsigned u = __float_as_uint(f);
  return (u + 0x7FFFu + ((u >> 16) & 1u)) >> 16;
}
__device__ __forceinline__ float bf16_to_f32(unsigned b) {
  return __uint_as_float(b << 16);
}

// ============ kernel 1: embedding gather + bf16 hi/lo pack ============
__global__ void emb_prep(const int* __restrict__ x, const float* __restrict__ emb,
                         unsigned* __restrict__ emb_hl) {
  int base = blockIdx.x * 4;
  int k = threadIdx.x;
  for (int it = 0; it < 4; ++it) {
    int tok = base + it;
    int id = x[tok];
    float w = emb[(size_t)id * EMBD + k];
    unsigned hb = bf16_rne(w);
    unsigned lb = bf16_rne(w - bf16_to_f32(hb));
    emb_hl[(size_t)tok * EMBD + k] = hb | (lb << 16);
  }
}

// ============ kernel 2: persistent LSTM recurrence ============
// 256 blocks (cooperative, 1/CU), 512 thr. group = blockIdx & 7 so that under
// round-robin dispatch each group's 32 blocks share one XCD (perf-only).
// All cross-block traffic (h words, counters) uses RELAXED agent-scope atomics:
// global_load/store with L2-bypass to the coherent L3 — NO buffer_inv/wbl2.
// Visibility: compiler emits s_waitcnt vmcnt(0) before every s_barrier, so all
// h stores are at L3 before tid0 bumps the step counter.
__global__ __launch_bounds__(512, 2) void lstm_persist(
    const float* __restrict__ Ww, const float* __restrict__ Wb,
    const unsigned* __restrict__ emb_hl,
    unsigned* __restrict__ h_hl, int* __restrict__ ctr,
    float* __restrict__ hfinal)
{
  __shared__ __align__(16) unsigned short u_hi[16 * UPITCH];
  __shared__ __align__(16) unsigned short u_lo[16 * UPITCH];
  __shared__ __align__(16) float red[8 * 4 * 64 * 4];   // [wave][ntile][lane][4]

  const int tid  = threadIdx.x;
  const int wave = tid >> 6;
  const int lane = tid & 63;
  const int g = blockIdx.x & 7;     // batch group 0..7  (XCD-local under rr)
  const int s = blockIdx.x >> 3;    // hidden slice 0..31

  for (int i = tid; i < 16 * UPITCH; i += 512) { u_hi[i] = 0; u_lo[i] = 0; }

  // ---- load W B-fragments into registers (one time) ----
  const int cn = lane & 15;
  const int qk = (lane >> 4) * 8;
  bf16x8 whi[3][4], wlo[3][4];
#pragma unroll
  for (int i = 0; i < 3; ++i) {
    int kt = wave * 3 + i;
    int k0 = kt * 32 + qk;
#pragma unroll
    for (int nt = 0; nt < 4; ++nt) {
      int row = nt * 512 + s * HS + cn;
      const float* src = Ww + (size_t)row * KTOT + k0;
      float4 w0 = *(const float4*)src;
      float4 w1 = *(const float4*)(src + 4);
      float wv[8] = {w0.x, w0.y, w0.z, w0.w, w1.x, w1.y, w1.z, w1.w};
#pragma unroll
      for (int j = 0; j < 8; ++j) {
        unsigned hb = bf16_rne(wv[j]);
        unsigned lb = bf16_rne(wv[j] - bf16_to_f32(hb));
        whi[i][nt][j] = (short)hb;
        wlo[i][nt][j] = (short)lb;
      }
    }
  }

  const float bias = Wb[(lane >> 4) * 512 + s * HS + (lane & 15)];
  const int rl = ((wave >> 2) << 4) | (lane & 15);
  const int rj = wave & 3;

  float Cst = 0.0f;  // cell state for (batch=wave, unit=lane) on lanes<16

  const unsigned* embg = emb_hl + (size_t)(g * GB) * STEPS * EMBD;
  unsigned* hbase = h_hl + (size_t)g * 3 * GB * HID;
  int* ctrg = ctr + g * STEPS;

  __syncthreads();

  for (int step = 0; step < STEPS; ++step) {
    // ---- stage emb (independent of h: overlaps the poll below) ----
    {
      int f0 = tid * 4;
      int b = f0 >> 8, k0 = f0 & 255;
      uint4 v = *(const uint4*)(embg + ((size_t)b * STEPS + step) * EMBD + k0);
      unsigned h01 = (v.x & 0xFFFFu) | ((v.y & 0xFFFFu) << 16);
      unsigned h23 = (v.z & 0xFFFFu) | ((v.w & 0xFFFFu) << 16);
      unsigned l01 = (v.x >> 16) | (v.y & 0xFFFF0000u);
      unsigned l23 = (v.z >> 16) | (v.w & 0xFFFF0000u);
      *(uint2*)&u_hi[b * UPITCH + k0] = make_uint2(h01, h23);
      *(uint2*)&u_lo[b * UPITCH + k0] = make_uint2(l01, l23);
    }
    // ---- wait for previous step's h from all 32 blocks of this group ----
    if (step > 0) {
      if (tid == 0) {
        while (__hip_atomic_load(&ctrg[step - 1], __ATOMIC_RELAXED,
                                 __HIP_MEMORY_SCOPE_AGENT) < BPG)
          __builtin_amdgcn_s_sleep(1);
        __atomic_signal_fence(__ATOMIC_ACQUIRE);
      }
    }
    __syncthreads();
    // ---- stage h_t (coherent L3 loads, L1/L2-bypass) ----
    {
      const unsigned* hin = hbase + (step % 3) * (GB * HID);
#pragma unroll
      for (int i = 0; i < GB; ++i) {
        unsigned v = __hip_atomic_load(&hin[i * HID + tid], __ATOMIC_RELAXED,
                                       __HIP_MEMORY_SCOPE_AGENT);
        u_hi[i * UPITCH + EMBD + tid] = (unsigned short)(v & 0xFFFFu);
        u_lo[i * UPITCH + EMBD + tid] = (unsigned short)(v >> 16);
      }
    }
    __syncthreads();

    // ---- gates = u @ W_sliceT : MFMA, k-split over waves ----
    f32x4 acc[4] = {{0.f,0.f,0.f,0.f},{0.f,0.f,0.f,0.f},
                    {0.f,0.f,0.f,0.f},{0.f,0.f,0.f,0.f}};
#pragma unroll
    for (int i = 0; i < 3; ++i) {
      int k0 = (wave * 3 + i) * 32 + qk;
      int m = lane & 15;
      bf16x8 ahi = *(const bf16x8*)&u_hi[m * UPITCH + k0];
      bf16x8 alo = *(const bf16x8*)&u_lo[m * UPITCH + k0];
#pragma unroll
      for (int nt = 0; nt < 4; ++nt) {
        acc[nt] = __builtin_amdgcn_mfma_f32_16x16x32_bf16(ahi, whi[i][nt], acc[nt], 0, 0, 0);
        acc[nt] = __builtin_amdgcn_mfma_f32_16x16x32_bf16(ahi, wlo[i][nt], acc[nt], 0, 0, 0);
        acc[nt] = __builtin_amdgcn_mfma_f32_16x16x32_bf16(alo, whi[i][nt], acc[nt], 0, 0, 0);
      }
    }
#pragma unroll
    for (int nt = 0; nt < 4; ++nt)
      *(f32x4*)&red[(((wave * 4 + nt) * 64) + lane) * 4] = acc[nt];
    __syncthreads();

    // ---- k-split reduction: thread owns (m=wave, n=lane) ----
    float gsum = bias;
#pragma unroll
    for (int w = 0; w < 8; ++w)
      gsum += red[(((w * 4 + (lane >> 4)) * 64) + rl) * 4 + rj];

    // ---- nonlinearities: lanes 0-15 f, 16-31 i, 32-47 o, 48-63 c~ ----
    float scl = (lane >= 48) ? 2.0f : 1.0f;
    float y = 1.0f / (1.0f + __expf(-gsum * scl));
    float act = (lane >= 48) ? (2.0f * y - 1.0f) : y;   // tanh via sigmoid
    float ig = __shfl(act, lane + 16);
    float og = __shfl(act, lane + 32);
    float cg = __shfl(act, lane + 48);
    if (lane < 16) {
      Cst = act * Cst + ig * cg;
      float t2 = 1.0f / (1.0f + __expf(-2.0f * Cst));
      float hv = og * (2.0f * t2 - 1.0f);
      unsigned hb = bf16_rne(hv);
      unsigned lb = bf16_rne(hv - bf16_to_f32(hb));
      unsigned* hout = hbase + ((step + 1) % 3) * (GB * HID);
      __hip_atomic_store(&hout[wave * HID + s * HS + lane], hb | (lb << 16),
                         __ATOMIC_RELAXED, __HIP_MEMORY_SCOPE_AGENT);
      if (step == STEPS - 1)
        hfinal[(size_t)(g * GB + wave) * HID + s * HS + lane] = hv;
    }
    // barrier drains every wave's h stores (s_waitcnt vmcnt(0) before s_barrier)
    __syncthreads();
    if (tid == 0) {
      __atomic_signal_fence(__ATOMIC_RELEASE);
      __hip_atomic_fetch_add(&ctrg[step], 1, __ATOMIC_RELAXED,
                             __HIP_MEMORY_SCOPE_AGENT);
    }
  }
}

// ============ kernel 3: out = h_final @ fcT + bias (MFMA hi/lo) ============
__device__ __forceinline__ void cvt8(const float4& a, const float4& b,
                                     bf16x8& hi, bf16x8& lo) {
  float v[8] = {a.x, a.y, a.z, a.w, b.x, b.y, b.z, b.w};
#pragma unroll
  for (int j = 0; j < 8; ++j) {
    unsigned hb = bf16_rne(v[j]);
    hi[j] = (short)hb;
    lo[j] = (short)bf16_rne(v[j] - bf16_to_f32(hb));
  }
}

__global__ __launch_bounds__(512) void fc_mfma(
    const float* __restrict__ hfinal, const float* __restrict__ fcw,
    const float* __restrict__ fcb, float* __restrict__ out)
{
  const int tid = threadIdx.x, wave = tid >> 6, lane = tid & 63;
  const int cn = lane & 15;
  const int qk = (lane >> 4) * 8;
  const int cls  = blockIdx.x * 128 + wave * 16 + cn;
  const int clsc = cls < NCLS ? cls : NCLS - 1;

  f32x4 acc[4] = {{0.f,0.f,0.f,0.f},{0.f,0.f,0.f,0.f},
                  {0.f,0.f,0.f,0.f},{0.f,0.f,0.f,0.f}};
#pragma unroll 2
  for (int kt = 0; kt < 16; ++kt) {
    int k0 = kt * 32 + qk;
    const float* bp = fcw + (size_t)clsc * HID + k0;
    float4 b0 = *(const float4*)bp;
    float4 b1 = *(const float4*)(bp + 4);
    bf16x8 bhi, blo;
    cvt8(b0, b1, bhi, blo);
#pragma unroll
    for (int mt = 0; mt < 4; ++mt) {
      const float* ap = hfinal + (size_t)(mt * 16 + cn) * HID + k0;
      float4 a0 = *(const float4*)ap;
      float4 a1 = *(const float4*)(ap + 4);
      bf16x8 ahi, alo;
      cvt8(a0, a1, ahi, alo);
      acc[mt] = __builtin_amdgcn_mfma_f32_16x16x32_bf16(ahi, bhi, acc[mt], 0, 0, 0);
      acc[mt] = __builtin_amdgcn_mfma_f32_16x16x32_bf16(ahi, blo, acc[mt], 0, 0, 0);
      acc[mt] = __builtin_amdgcn_mfma_f32_16x16x32_bf16(alo, bhi, acc[mt], 0, 0, 0);
    }
  }
  if (cls < NCLS) {
    float bias = fcb[cls];
#pragma unroll
    for (int mt = 0; mt < 4; ++mt)
#pragma unroll
      for (int j = 0; j < 4; ++j) {
        int m = mt * 16 + (lane >> 4) * 4 + j;
        out[(size_t)m * NCLS + cls] = acc[mt][j] + bias;
      }
  }
}

// ============ launcher ============
extern "C" void kernel_launch(void* const* d_in, const int* in_sizes, int n_in,
                              void* d_out, int out_size, void* d_ws, size_t ws_size,
                              hipStream_t stream) {
  const int*   x   = (const int*)d_in[0];
  const float* emb = (const float*)d_in[1];
  const float* Ww  = (const float*)d_in[2];
  const float* Wb  = (const float*)d_in[3];
  const float* fcw = (const float*)d_in[4];
  const float* fcb = (const float*)d_in[5];
  float* out = (float*)d_out;

  char* ws = (char*)d_ws;
  int*      ctr    = (int*)ws;                                  //  16,384 B
  unsigned* h_hl   = (unsigned*)(ws + 16384);                   // 393,216 B
  float*    hfinal = (float*)(ws + 16384 + 393216);             // 131,072 B
  unsigned* emb_hl = (unsigned*)(ws + 16384 + 393216 + 131072); // 33.5 MB

  hipMemsetAsync(d_ws, 0, 16384 + 393216, stream);

  emb_prep<<<8192, 256, 0, stream>>>(x, emb, emb_hl);

  void* args[] = { (void*)&Ww, (void*)&Wb, (void*)&emb_hl,
                   (void*)&h_hl, (void*)&ctr, (void*)&hfinal };
  hipLaunchCooperativeKernel((void*)lstm_persist, dim3(256), dim3(512),
                             args, 0, stream);

  fc_mfma<<<(NCLS + 127) / 128, 512, 0, stream>>>(hfinal, fcw, fcb, out);
}

// Round 3
// 2042.655 us; speedup vs baseline: 10.7900x; 1.1085x over previous
//
#include <hip/hip_runtime.h>
#include <stdint.h>

// ---------------- problem constants ----------------
#define EMBD   256
#define HID    512
#define KTOT   768            // EMB + HID
#define NCLS   50257
#define STEPS  512

// ---------------- persistent-kernel partition ----------------
#define NGROUP 8               // batch groups
#define GB     8               // batches per group
#define BPG    32              // blocks per group (hidden split)
#define HS     16              // hidden units per block -> 64 gate rows
#define UPITCH 776             // u row pitch in bf16 elems (768 + 8 pad)
#define RP     129             // red tile pitch in floats (129 mod 32 = 1 -> conflict-free)

typedef float f32x4  __attribute__((ext_vector_type(4)));
typedef short bf16x8 __attribute__((ext_vector_type(8)));
typedef unsigned long long u64;

__device__ __forceinline__ unsigned bf16_rne(float f) {
  unsigned u = __float_as_uint(f);
  return (u + 0x7FFFu + ((u >> 16) & 1u)) >> 16;
}
__device__ __forceinline__ float bf16_to_f32(unsigned b) {
  return __uint_as_float(b << 16);
}

// ============ kernel 1: embedding gather + bf16 hi/lo pack ============
__global__ void emb_prep(const int* __restrict__ x, const float* __restrict__ emb,
                         unsigned* __restrict__ emb_hl) {
  int base = blockIdx.x * 4;
  int k = threadIdx.x;
  for (int it = 0; it < 4; ++it) {
    int tok = base + it;
    int id = x[tok];
    float w = emb[(size_t)id * EMBD + k];
    unsigned hb = bf16_rne(w);
    unsigned lb = bf16_rne(w - bf16_to_f32(hb));
    emb_hl[(size_t)tok * EMBD + k] = hb | (lb << 16);
  }
}

// ============ kernel 2: persistent LSTM recurrence ============
// 256 blocks (cooperative), 512 thr. group g = blockIdx&7 (XCD-local, perf only).
// h exchange is SELF-SYNCHRONIZING: each h word is a u64 {tag=step+1 | hi|lo}
// stored with one relaxed agent-scope 8B atomic (single-copy atomic, L2-bypass
// to coherent L3). No counters, no RMW, no fences on the critical path.
// Double-buffer by step parity: a block writes step+1 only after consuming all
// of step, which proves every block finished reading step-1 (the data being
// overwritten). Tag match therefore implies data validity.
__global__ __launch_bounds__(512, 2) void lstm_persist(
    const float* __restrict__ Ww, const float* __restrict__ Wb,
    const unsigned* __restrict__ emb_hl,
    u64* __restrict__ hbuf,
    unsigned short* __restrict__ h_hi, unsigned short* __restrict__ h_lo)
{
  __shared__ __align__(16) unsigned short u_hi[16 * UPITCH];
  __shared__ __align__(16) unsigned short u_lo[16 * UPITCH];
  __shared__ __align__(16) float red[32 * RP];   // [wave*4+nt][lane<32][4] padded

  const int tid  = threadIdx.x;
  const int wave = tid >> 6;
  const int lane = tid & 63;
  const int g = blockIdx.x & 7;     // batch group 0..7  (XCD-local under rr)
  const int s = blockIdx.x >> 3;    // hidden slice 0..31

  // zero u rows once (rows 8..15 are M-padding and stay zero forever)
  for (int i = tid; i < 16 * UPITCH; i += 512) { u_hi[i] = 0; u_lo[i] = 0; }

  // ---- load W B-fragments into registers (one time) ----
  const int cn = lane & 15;
  const int qk = (lane >> 4) * 8;
  bf16x8 whi[3][4], wlo[3][4];
#pragma unroll
  for (int i = 0; i < 3; ++i) {
    int kt = wave * 3 + i;
    int k0 = kt * 32 + qk;
#pragma unroll
    for (int nt = 0; nt < 4; ++nt) {
      int row = nt * 512 + s * HS + cn;
      const float* src = Ww + (size_t)row * KTOT + k0;
      float4 w0 = *(const float4*)src;
      float4 w1 = *(const float4*)(src + 4);
      float wv[8] = {w0.x, w0.y, w0.z, w0.w, w1.x, w1.y, w1.z, w1.w};
#pragma unroll
      for (int j = 0; j < 8; ++j) {
        unsigned hb = bf16_rne(wv[j]);
        unsigned lb = bf16_rne(wv[j] - bf16_to_f32(hb));
        whi[i][nt][j] = (short)hb;
        wlo[i][nt][j] = (short)lb;
      }
    }
  }

  const float bias = Wb[(lane >> 4) * 512 + s * HS + (lane & 15)];

  float Cst = 0.0f;  // cell state for (batch=wave, unit=lane) on lanes<16

  const unsigned* embg = emb_hl + (size_t)(g * GB) * STEPS * EMBD;
  u64* hg = hbuf + (size_t)g * 2 * GB * HID;

  __syncthreads();

  for (int step = 0; step < STEPS; ++step) {
    // ---- stage emb (independent of h: load issued before the poll) ----
    {
      int f0 = tid * 4;
      int b = f0 >> 8, k0 = f0 & 255;
      uint4 v = *(const uint4*)(embg + ((size_t)b * STEPS + step) * EMBD + k0);
      unsigned h01 = (v.x & 0xFFFFu) | ((v.y & 0xFFFFu) << 16);
      unsigned h23 = (v.z & 0xFFFFu) | ((v.w & 0xFFFFu) << 16);
      unsigned l01 = (v.x >> 16) | (v.y & 0xFFFF0000u);
      unsigned l23 = (v.z >> 16) | (v.w & 0xFFFF0000u);
      *(uint2*)&u_hi[b * UPITCH + k0] = make_uint2(h01, h23);
      *(uint2*)&u_lo[b * UPITCH + k0] = make_uint2(l01, l23);
    }
    // ---- poll + stage h: wave w handles batch w, lane covers 8 units ----
    {
      const u64* hp = hg + ((size_t)(step & 1) * GB + wave) * HID + lane * 8;
      u64 v[8];
      const unsigned want = (unsigned)step;
      while (true) {
        bool ok = true;
#pragma unroll
        for (int j = 0; j < 8; ++j)
          v[j] = __hip_atomic_load(&hp[j], __ATOMIC_RELAXED,
                                   __HIP_MEMORY_SCOPE_AGENT);
#pragma unroll
        for (int j = 0; j < 8; ++j)
          ok &= ((unsigned)(v[j] >> 32) == want);
        if (ok) break;
        __builtin_amdgcn_s_sleep(1);
      }
      bf16x8 hh, hl;
#pragma unroll
      for (int j = 0; j < 8; ++j) {
        unsigned w32 = (unsigned)v[j];
        hh[j] = (short)(w32 & 0xFFFFu);
        hl[j] = (short)(w32 >> 16);
      }
      *(bf16x8*)&u_hi[wave * UPITCH + EMBD + lane * 8] = hh;
      *(bf16x8*)&u_lo[wave * UPITCH + EMBD + lane * 8] = hl;
    }
    __syncthreads();

    // ---- gates = u @ W_sliceT : MFMA, k-split 8 ways over waves ----
    f32x4 acc[4] = {{0.f,0.f,0.f,0.f},{0.f,0.f,0.f,0.f},
                    {0.f,0.f,0.f,0.f},{0.f,0.f,0.f,0.f}};
#pragma unroll
    for (int i = 0; i < 3; ++i) {
      int k0 = (wave * 3 + i) * 32 + qk;
      int m = lane & 15;
      bf16x8 ahi = *(const bf16x8*)&u_hi[m * UPITCH + k0];
      bf16x8 alo = *(const bf16x8*)&u_lo[m * UPITCH + k0];
#pragma unroll
      for (int nt = 0; nt < 4; ++nt) {
        acc[nt] = __builtin_amdgcn_mfma_f32_16x16x32_bf16(ahi, whi[i][nt], acc[nt], 0, 0, 0);
        acc[nt] = __builtin_amdgcn_mfma_f32_16x16x32_bf16(ahi, wlo[i][nt], acc[nt], 0, 0, 0);
        acc[nt] = __builtin_amdgcn_mfma_f32_16x16x32_bf16(alo, whi[i][nt], acc[nt], 0, 0, 0);
      }
    }
    // only lanes<32 hold valid rows (m=0..7); pitch 129 kills bank conflicts
    if (lane < 32) {
#pragma unroll
      for (int nt = 0; nt < 4; ++nt)
        *(f32x4*)&red[(wave * 4 + nt) * RP + lane * 4] = acc[nt];
    }
    __syncthreads();

    // ---- k-split reduction: thread owns (batch=wave, gate-row=lane) ----
    float gsum = bias;
    {
      int tq = lane >> 4;
      int rbase = ((((wave >> 2) << 4) | (lane & 15)) << 2) + (wave & 3);
#pragma unroll
      for (int w = 0; w < 8; ++w)
        gsum += red[(w * 4 + tq) * RP + rbase];
    }

    // ---- nonlinearities: lanes 0-15 f, 16-31 i, 32-47 o, 48-63 c~ ----
    float scl = (lane >= 48) ? 2.0f : 1.0f;
    float y = 1.0f / (1.0f + __expf(-gsum * scl));
    float act = (lane >= 48) ? (2.0f * y - 1.0f) : y;   // tanh via sigmoid
    float ig = __shfl(act, lane + 16);
    float og = __shfl(act, lane + 32);
    float cg = __shfl(act, lane + 48);
    if (lane < 16) {
      Cst = act * Cst + ig * cg;
      float t2 = 1.0f / (1.0f + __expf(-2.0f * Cst));
      float hv = og * (2.0f * t2 - 1.0f);
      unsigned hb = bf16_rne(hv);
      unsigned lb = bf16_rne(hv - bf16_to_f32(hb));
      u64 pack = ((u64)(unsigned)(step + 1) << 32) | (u64)(hb | (lb << 16));
      __hip_atomic_store(
          &hg[((size_t)((step + 1) & 1) * GB + wave) * HID + s * HS + lane],
          pack, __ATOMIC_RELAXED, __HIP_MEMORY_SCOPE_AGENT);
      if (step == STEPS - 1) {
        int m = g * GB + wave, k = s * HS + lane;
        h_hi[m * HID + k] = (unsigned short)hb;
        h_lo[m * HID + k] = (unsigned short)lb;
      }
    }
    // no trailing barrier: next iteration's syncthreads protects LDS reuse
  }
}

// ============ kernel 3: out = h_final @ fcT + bias (MFMA hi/lo) ============
__device__ __forceinline__ void cvt8(const float4& a, const float4& b,
                                     bf16x8& hi, bf16x8& lo) {
  float v[8] = {a.x, a.y, a.z, a.w, b.x, b.y, b.z, b.w};
#pragma unroll
  for (int j = 0; j < 8; ++j) {
    unsigned hb = bf16_rne(v[j]);
    hi[j] = (short)hb;
    lo[j] = (short)bf16_rne(v[j] - bf16_to_f32(hb));
  }
}

__global__ __launch_bounds__(512) void fc_mfma(
    const unsigned short* __restrict__ h_hi, const unsigned short* __restrict__ h_lo,
    const float* __restrict__ fcw, const float* __restrict__ fcb,
    float* __restrict__ out)
{
  const int tid = threadIdx.x, wave = tid >> 6, lane = tid & 63;
  const int cn = lane & 15;
  const int qk = (lane >> 4) * 8;
  const int cls  = blockIdx.x * 128 + wave * 16 + cn;
  const int clsc = cls < NCLS ? cls : NCLS - 1;

  f32x4 acc[4] = {{0.f,0.f,0.f,0.f},{0.f,0.f,0.f,0.f},
                  {0.f,0.f,0.f,0.f},{0.f,0.f,0.f,0.f}};
#pragma unroll 2
  for (int kt = 0; kt < 16; ++kt) {
    int k0 = kt * 32 + qk;
    const float* bp = fcw + (size_t)clsc * HID + k0;
    float4 b0 = *(const float4*)bp;
    float4 b1 = *(const float4*)(bp + 4);
    bf16x8 bhi, blo;
    cvt8(b0, b1, bhi, blo);
#pragma unroll
    for (int mt = 0; mt < 4; ++mt) {
      bf16x8 ahi = *(const bf16x8*)&h_hi[(size_t)(mt * 16 + cn) * HID + k0];
      bf16x8 alo = *(const bf16x8*)&h_lo[(size_t)(mt * 16 + cn) * HID + k0];
      acc[mt] = __builtin_amdgcn_mfma_f32_16x16x32_bf16(ahi, bhi, acc[mt], 0, 0, 0);
      acc[mt] = __builtin_amdgcn_mfma_f32_16x16x32_bf16(ahi, blo, acc[mt], 0, 0, 0);
      acc[mt] = __builtin_amdgcn_mfma_f32_16x16x32_bf16(alo, bhi, acc[mt], 0, 0, 0);
    }
  }
  if (cls < NCLS) {
    float bias = fcb[cls];
#pragma unroll
    for (int mt = 0; mt < 4; ++mt)
#pragma unroll
      for (int j = 0; j < 4; ++j) {
        int m = mt * 16 + (lane >> 4) * 4 + j;
        out[(size_t)m * NCLS + cls] = acc[mt][j] + bias;
      }
  }
}

// ============ launcher ============
extern "C" void kernel_launch(void* const* d_in, const int* in_sizes, int n_in,
                              void* d_out, int out_size, void* d_ws, size_t ws_size,
                              hipStream_t stream) {
  const int*   x   = (const int*)d_in[0];
  const float* emb = (const float*)d_in[1];
  const float* Ww  = (const float*)d_in[2];
  const float* Wb  = (const float*)d_in[3];
  const float* fcw = (const float*)d_in[4];
  const float* fcb = (const float*)d_in[5];
  float* out = (float*)d_out;

  // workspace carve-up
  char* ws = (char*)d_ws;
  u64*            hbuf   = (u64*)ws;                          // 524,288 B (8g x 2slot x 8b x 512 x 8B)
  unsigned short* h_hi   = (unsigned short*)(ws + 524288);    //  65,536 B
  unsigned short* h_lo   = (unsigned short*)(ws + 524288 + 65536);
  unsigned*       emb_hl = (unsigned*)(ws + 524288 + 131072); // 33.5 MB

  // zero h exchange buffer: tag=0 == "h for step 0 valid and zero"
  hipMemsetAsync(hbuf, 0, 524288, stream);

  emb_prep<<<8192, 256, 0, stream>>>(x, emb, emb_hl);

  void* args[] = { (void*)&Ww, (void*)&Wb, (void*)&emb_hl,
                   (void*)&hbuf, (void*)&h_hi, (void*)&h_lo };
  hipLaunchCooperativeKernel((void*)lstm_persist, dim3(256), dim3(512),
                             args, 0, stream);

  fc_mfma<<<(NCLS + 127) / 128, 512, 0, stream>>>(h_hi, h_lo, fcw, fcb, out);
}